// Round 11
// baseline (63.153 us; speedup 1.0000x reference)
//
#include <hip/hip_runtime.h>

// N=8192, d_model=2048, h=16, d_k=128.
// softmax over a size-1 axis == 1.0 exactly -> head_out[h,n,:] = v_proj[h,0,:].
// out[n][m] = r[m],  r = vp @ Wo,  vp[h*128+k] = sum_d v_param[d]*Wv[h,d,k].
//
// TWO nodes:
//  k12 (512 blk x 256): every block is BOTH producer and consumer.
//   producer (h=b&15, ds=b>>4): Wv float4 loads -> part1[ds][head h slice]
//     via sc1 write-through; blocks 0..7 also zero r; t0 signals done[h]
//     (+1 to every head for zeroers; target 32 producers + 8 zeroers = 40).
//   consumer (ms=b&31, jq=b>>5): issue 8 float4 Wo loads (in flight during
//     the wait), RMW-poll done[jq]>=40 (16 addrs, <=32 pollers, s_sleep(64)
//     -> ~19 RMW/us/addr, under IC RMW capacity; R8's 1-addr/512-poller
//     storm is what cost 25us/barrier), then vp from part1 (IC loads),
//     dot with Wo regs, LDS reduce, atomicAdd into r.
//  k_bcast (512 blk): broadcast r to 16 rows/block, float4 stores (64 MB).
//
// done[] self-sanitizes across graph replays (CAS poison->0, 40->0 before
// any signal; all 512 blocks are co-resident (2/CU) and CAS within ~0.1us
// while the first signal needs ~2.5us of HBM reads — R6-R8 precedent).

#define DM     2048
#define H      16
#define DK     128
#define POISON 0xAAAAAAAAu
#define TARGET 40u   // 32 producers + 8 zeroers

__device__ __forceinline__ void fma4(float4& a, float s, const float4& w) {
    a.x += s * w.x; a.y += s * w.y; a.z += s * w.z; a.w += s * w.w;
}
__device__ __forceinline__ float ld_coh(const float* p) {
    return __hip_atomic_load(p, __ATOMIC_RELAXED, __HIP_MEMORY_SCOPE_AGENT);
}
__device__ __forceinline__ void st_coh(float* p, float v) {
    __hip_atomic_store(p, v, __ATOMIC_RELAXED, __HIP_MEMORY_SCOPE_AGENT);
}

__global__ __launch_bounds__(256, 2) void k12(
    const float* __restrict__ Wv,
    const float* __restrict__ vparam,
    const float* __restrict__ Wo,
    float* __restrict__ part1,        // [32][2048]
    float* __restrict__ r,            // [2048]
    unsigned int* __restrict__ done)  // [16]
{
    const int b = blockIdx.x;
    const int t = threadIdx.x;

    // sanitize flags (poison on first launch, TARGET on replays)
    if (t < 16) {
        atomicCAS(&done[t], POISON, 0u);
        atomicCAS(&done[t], TARGET, 0u);
    }

    // ---- producer: Wv partial v-projection for head h, d-seg ds ----
    const int h  = b & 15;
    const int ds = b >> 4;              // 0..31 (64 d's)
    const int k4 = t & 31;              // k = 4*k4..+3
    const int dg = t >> 5;              // 0..7 (8 d's each)
    const int d0 = ds * 64 + dg * 8;
    {
        const float* base = Wv + ((size_t)h * DM + d0) * DK + 4 * k4;
        float4 acc = {0.f, 0.f, 0.f, 0.f};
#pragma unroll
        for (int i = 0; i < 8; ++i)
            fma4(acc, vparam[d0 + i], *(const float4*)(base + (size_t)i * DK));
        __shared__ float4 sred[8][32];
        sred[dg][k4] = acc;
        __syncthreads();
        if (t < 32) {
            float4 s = sred[0][t];
#pragma unroll
            for (int g = 1; g < 8; ++g) {
                const float4 v = sred[g][t];
                s.x += v.x; s.y += v.y; s.z += v.z; s.w += v.w;
            }
            float* dst = part1 + (size_t)ds * DM + h * DK + 4 * t;
            st_coh(dst + 0, s.x); st_coh(dst + 1, s.y);
            st_coh(dst + 2, s.z); st_coh(dst + 3, s.w);
        }
    }
    if (b < 8) st_coh(&r[(b << 8) + t], 0.f);   // zero accumulator

    __syncthreads();                    // vmcnt(0): wt-stores visible at IC
    if (t == 0) {
        __hip_atomic_fetch_add(&done[h], 1u, __ATOMIC_RELAXED,
                               __HIP_MEMORY_SCOPE_AGENT);
        if (b < 8)
#pragma unroll
            for (int i = 0; i < 16; ++i)
                __hip_atomic_fetch_add(&done[i], 1u, __ATOMIC_RELAXED,
                                       __HIP_MEMORY_SCOPE_AGENT);
    }

    // ---- consumer: issue Wo prefetch BEFORE polling (hides the read) ----
    const int ms = b & 31;              // cols ms*64 .. +64
    const int jq = b >> 5;              // head jq: j's jq*128 .. +128
    const int m4 = t & 15;              // 4 cols
    const int jg = t >> 4;              // 0..15 (j-groups of 8)
    float4 w[8];
    {
        const float* wop = Wo + (size_t)(jq * 128 + jg * 8) * DM + ms * 64 + 4 * m4;
#pragma unroll
        for (int i = 0; i < 8; ++i) w[i] = *(const float4*)(wop + (size_t)i * DM);
    }

    // ---- poll: fresh RMW read of done[jq]; 16 addrs, <=32 pollers each ----
    if (t == 0) {
        int it = 0;
        do {
            unsigned v = __hip_atomic_fetch_add(&done[jq], 0u, __ATOMIC_RELAXED,
                                                __HIP_MEMORY_SCOPE_AGENT);
            if (v >= TARGET) break;
            __builtin_amdgcn_s_sleep(64);
        } while (++it < (1 << 16));
    }
    __syncthreads();

    // ---- consume: vp slice for head jq from part1 (IC loads) ----
    __shared__ float vph[2][128];
    __shared__ float vp_s[128];
    {
        const int jl = t & 127;
        const int hf = t >> 7;
        const float* p = part1 + (size_t)(hf * 16) * DM + jq * 128 + jl;
        float s = 0.f;
#pragma unroll
        for (int c = 0; c < 16; ++c) s += ld_coh(&p[(size_t)c * DM]);
        vph[hf][jl] = s;
    }
    __syncthreads();
    if (t < 128) vp_s[t] = vph[0][t] + vph[1][t];
    __syncthreads();

    // ---- dot with prefetched Wo, reduce, accumulate into r ----
    float4 a2 = {0.f, 0.f, 0.f, 0.f};
#pragma unroll
    for (int i = 0; i < 8; ++i) fma4(a2, vp_s[jg * 8 + i], w[i]);
    __shared__ float4 red4[16][16];
    red4[jg][m4] = a2;
    __syncthreads();
    if (t < 64) {
        const int mm = t & 15;
        const int cc = t >> 4;
        float s = 0.f;
#pragma unroll
        for (int g = 0; g < 16; ++g) s += ((const float*)&red4[g][mm])[cc];
        atomicAdd(&r[ms * 64 + 4 * mm + cc], s);
    }
}

// k_bcast: broadcast r to 16 rows per block, float4 stores (write-BW-bound).
__global__ __launch_bounds__(256) void k_bcast(const float* __restrict__ r,
                                               float* __restrict__ out) {
    const int b = blockIdx.x;           // 0..511
    const int t = threadIdx.x;
    const float4 v0 = ((const float4*)r)[t];
    const float4 v1 = ((const float4*)r)[256 + t];
    float4* o4 = (float4*)out + (size_t)b * 16 * (DM / 4);
#pragma unroll
    for (int n = 0; n < 16; ++n) {
        o4[(size_t)n * (DM / 4) + t]       = v0;
        o4[(size_t)n * (DM / 4) + 256 + t] = v1;
    }
}

extern "C" void kernel_launch(void* const* d_in, const int* in_sizes, int n_in,
                              void* d_out, int out_size, void* d_ws, size_t ws_size,
                              hipStream_t stream) {
    // inputs: 0=q, 1=Wq, 2=Wk, 3=Wv, 4=k_param, 5=v_param, 6=Wo (all fp32)
    const float* Wv     = (const float*)d_in[3];
    const float* vparam = (const float*)d_in[5];
    const float* Wo     = (const float*)d_in[6];
    float* out = (float*)d_out;

    float* part1       = (float*)d_ws;            // 32*2048 floats = 256 KB
    float* r           = part1 + 32 * DM;         // 2048 floats
    unsigned int* done = (unsigned int*)(r + DM); // 16 uints

    k12    <<<512, 256, 0, stream>>>(Wv, vparam, Wo, part1, r, done);
    k_bcast<<<512, 256, 0, stream>>>(r, out);
}